// Round 4
// baseline (134.691 us; speedup 1.0000x reference)
//
#include <hip/hip_runtime.h>
#include <math.h>

typedef float2 cplx;
__device__ __forceinline__ cplx mk(float r, float i){ return make_float2(r, i); }

// Fused conv iteration on a 16-amp half-group in registers, over a 1024-amp
// LDS array with swizzle phys = l ^ ((l>>5)&31).
// Window bits LO..LO+4: bit LO+4 = wire i, LO+3 = i+1, LO+2 = i+2 (untouched,
// split bit c), LO+1 = i+3, LO = i+4. Register index m: [3]=i,[2]=i+1,[1]=i+3,[0]=i+4.
template<int LO>
__device__ __forceinline__ void do_iter(cplx* S, int g, int c,
    float hc0, float hs0, float hc1, float hs1, float hc2, float hs2,
    float hcx, float hsx, float hc4, float hs4)
{
  const int base = ((g >> LO) << (LO + 5)) | (g & ((1 << LO) - 1)) | (c << (LO + 2));
  cplx A[16];
  int la[16];
  #pragma unroll
  for (int m = 0; m < 16; ++m){
    int off = (((m >> 3) & 1) << (LO + 4)) | (((m >> 2) & 1) << (LO + 3))
            | (((m >> 1) & 1) << (LO + 1)) | ((m & 1) << LO);
    int l = base | off;
    la[m] = l ^ ((l >> 5) & 31);
    A[m] = S[la[m]];
  }
  // G1: RY0 on wire i (bit 3)
  #pragma unroll
  for (int p = 0; p < 8; ++p){
    cplx a0 = A[p], a1 = A[p | 8];
    A[p]     = mk(hc0*a0.x - hs0*a1.x, hc0*a0.y - hs0*a1.y);
    A[p | 8] = mk(hs0*a0.x + hc0*a1.x, hs0*a0.y + hc0*a1.y);
  }
  // G2: CNOT(i -> i+3) then RY1 on i+3. ctl bit 3, tgt bit 1.
  #pragma unroll
  for (int q = 0; q < 16; ++q){
    if (q & 2) continue;
    cplx a0 = A[q], a1 = A[q | 2];
    if (q & 8){
      A[q]     = mk(-hs1*a0.x + hc1*a1.x, -hs1*a0.y + hc1*a1.y);
      A[q | 2] = mk( hc1*a0.x + hs1*a1.x,  hc1*a0.y + hs1*a1.y);
    } else {
      A[q]     = mk( hc1*a0.x - hs1*a1.x,  hc1*a0.y - hs1*a1.y);
      A[q | 2] = mk( hs1*a0.x + hc1*a1.x,  hs1*a0.y + hc1*a1.y);
    }
  }
  // G3: RY2 on i+1 (bit 2); CNOT(i+1 -> i+4); RX0 on i+4 (bit 0)
  #pragma unroll
  for (int r = 0; r < 16; ++r){
    if (r & 5) continue;
    cplx a00 = A[r], a01 = A[r | 1], a10 = A[r | 4], a11 = A[r | 5];
    cplx b00 = mk(hc2*a00.x - hs2*a10.x, hc2*a00.y - hs2*a10.y);
    cplx b01 = mk(hc2*a01.x - hs2*a11.x, hc2*a01.y - hs2*a11.y);
    cplx b10 = mk(hs2*a00.x + hc2*a10.x, hs2*a00.y + hc2*a10.y);
    cplx b11 = mk(hs2*a01.x + hc2*a11.x, hs2*a01.y + hc2*a11.y);
    cplx c10 = b11, c11 = b10;
    A[r]     = mk(hcx*b00.x + hsx*b01.y,  hcx*b00.y - hsx*b01.x);
    A[r | 1] = mk(hsx*b00.y + hcx*b01.x, -hsx*b00.x + hcx*b01.y);
    A[r | 4] = mk(hcx*c10.x + hsx*c11.y,  hcx*c10.y - hsx*c11.x);
    A[r | 5] = mk(hsx*c10.y + hcx*c11.x, -hsx*c10.x + hcx*c11.y);
  }
  // G4: CNOT(i+3 -> i+1) then RX1 on i+1. ctl bit 1, tgt bit 2.
  #pragma unroll
  for (int q = 0; q < 16; ++q){
    if (q & 4) continue;
    cplx a0 = A[q], a1 = A[q | 4];
    if (q & 2){
      A[q]     = mk( hs4*a0.y + hc4*a1.x, -hs4*a0.x + hc4*a1.y);
      A[q | 4] = mk( hc4*a0.x + hs4*a1.y,  hc4*a0.y - hs4*a1.x);
    } else {
      A[q]     = mk( hc4*a0.x + hs4*a1.y,  hc4*a0.y - hs4*a1.x);
      A[q | 4] = mk( hs4*a0.y + hc4*a1.x, -hs4*a0.x + hc4*a1.y);
    }
  }
  #pragma unroll
  for (int m = 0; m < 16; ++m) S[la[m]] = A[m];
}

// Kernel A: per (b,k) pair, evolve the wires-0..9 sub-state (iterations 0..5),
// write Psi (1024 cplx) to global. Block 0 also zeroes acc. 32 blocks x 64 thr.
__global__ __launch_bounds__(64) void stage1_kernel(
    const float* __restrict__ x, const float* __restrict__ kp,
    cplx* __restrict__ psi_g, float* __restrict__ cs, float* __restrict__ acc)
{
  __shared__ cplx Psi[1024];
  __shared__ float vc[16], vs[16];
  const int t = threadIdx.x;
  const int pair = blockIdx.x;
  const int b = pair & 15, k = pair >> 4;

  if (pair == 0){
    for (int e = t; e < 384; e += 64) acc[e] = 0.f;
  }

  if (t < 16){
    int i = t >> 2, j = t & 3;
    const float* xb = x + b*784 + (7*i)*28 + 7*j;
    float s = 0.f;
    #pragma unroll
    for (int u = 0; u < 7; ++u)
      #pragma unroll
      for (int v = 0; v < 7; ++v)
        s += xb[u*28 + v];
    float ang = s * (1.0f/49.0f) * 0.5f;
    vc[t] = cosf(ang);
    vs[t] = sinf(ang);
    if (k == 0){ cs[b*32 + t] = vc[t]; cs[b*32 + 16 + t] = vs[t]; }
  }
  __syncthreads();

  // Psi0: product over wires 0..9 (Psi bit 9-w), swizzled store
  #pragma unroll
  for (int j = 0; j < 16; ++j){
    int h = t + 64*j;
    float p = 1.f;
    #pragma unroll
    for (int w = 0; w < 10; ++w)
      p *= ((h >> (9 - w)) & 1) ? vs[w] : vc[w];
    Psi[h ^ ((h >> 5) & 31)] = mk(p, 0.f);
  }

  const float* p5 = kp + k*5;
  float hc0 = cosf(p5[0]*0.5f), hs0 = sinf(p5[0]*0.5f);
  float hc1 = cosf(p5[1]*0.5f), hs1 = sinf(p5[1]*0.5f);
  float hc2 = cosf(p5[2]*0.5f), hs2 = sinf(p5[2]*0.5f);
  float hcx = cosf(p5[3]*0.5f), hsx = sinf(p5[3]*0.5f);
  float hc4 = cosf(p5[4]*0.5f), hs4 = sinf(p5[4]*0.5f);
  __syncthreads();

  // iterations 0..5: wire w -> bit 9-w, iter i -> LO = 5-i
  int g = t & 31, c = t >> 5;
  do_iter<5>(Psi,g,c,hc0,hs0,hc1,hs1,hc2,hs2,hcx,hsx,hc4,hs4); __syncthreads();
  do_iter<4>(Psi,g,c,hc0,hs0,hc1,hs1,hc2,hs2,hcx,hsx,hc4,hs4); __syncthreads();
  do_iter<3>(Psi,g,c,hc0,hs0,hc1,hs1,hc2,hs2,hcx,hsx,hc4,hs4); __syncthreads();
  do_iter<2>(Psi,g,c,hc0,hs0,hc1,hs1,hc2,hs2,hcx,hsx,hc4,hs4); __syncthreads();
  do_iter<1>(Psi,g,c,hc0,hs0,hc1,hs1,hc2,hs2,hcx,hsx,hc4,hs4); __syncthreads();
  do_iter<0>(Psi,g,c,hc0,hs0,hc1,hs1,hc2,hs2,hcx,hsx,hc4,hs4); __syncthreads();

  #pragma unroll
  for (int j = 0; j < 16; ++j){
    int h = t + 64*j;
    psi_g[pair*1024 + h] = Psi[h ^ ((h >> 5) & 31)];
  }
}

// Kernel B: 2048 single-wave blocks. blk = pair*64 + chunk; chunk = wires 0..5
// (global bits 15..10). Local l = global bits 9..0; wire w -> local bit 15-w.
__global__ __launch_bounds__(64) void stage3_kernel(
    const cplx* __restrict__ psi_g, const float* __restrict__ cs,
    const float* __restrict__ kp, float* __restrict__ acc)
{
  __shared__ cplx S[1024];
  __shared__ cplx PsiW[16];
  __shared__ float Pre[64];
  const int t = threadIdx.x;
  const int blk = blockIdx.x;
  const int chunk = blk & 63;
  const int pair = blk >> 6;
  const int b = pair & 15, k = pair >> 4;

  if (t < 16) PsiW[t] = psi_g[pair*1024 + (chunk << 4) + t];
  // Pre over wires 10..15 (local bits 5..0)
  {
    float p = 1.f;
    #pragma unroll
    for (int w = 10; w < 16; ++w){
      float c0 = cs[b*32 + w], s0 = cs[b*32 + 16 + w];
      p *= ((t >> (15 - w)) & 1) ? s0 : c0;
    }
    Pre[t] = p;
  }

  const float* p5 = kp + k*5;
  float hc0 = cosf(p5[0]*0.5f), hs0 = sinf(p5[0]*0.5f);
  float hc1 = cosf(p5[1]*0.5f), hs1 = sinf(p5[1]*0.5f);
  float hc2 = cosf(p5[2]*0.5f), hs2 = sinf(p5[2]*0.5f);
  float hcx = cosf(p5[3]*0.5f), hsx = sinf(p5[3]*0.5f);
  float hc4 = cosf(p5[4]*0.5f), hs4 = sinf(p5[4]*0.5f);
  __syncthreads();

  // expand: S[l] = Psi[(chunk<<4)|(l>>6)] * Pre[l&63]
  #pragma unroll
  for (int j = 0; j < 16; ++j){
    int l = t + 64*j;
    cplx ph = PsiW[l >> 6];
    float pr = Pre[l & 63];
    S[l ^ ((l >> 5) & 31)] = mk(ph.x * pr, ph.y * pr);
  }
  __syncthreads();

  // iterations 6..11: wire w -> local bit 15-w, iter i -> LO = 11-i
  int g = t & 31, c = t >> 5;
  do_iter<5>(S,g,c,hc0,hs0,hc1,hs1,hc2,hs2,hcx,hsx,hc4,hs4); __syncthreads();
  do_iter<4>(S,g,c,hc0,hs0,hc1,hs1,hc2,hs2,hcx,hsx,hc4,hs4); __syncthreads();
  do_iter<3>(S,g,c,hc0,hs0,hc1,hs1,hc2,hs2,hcx,hsx,hc4,hs4); __syncthreads();
  do_iter<2>(S,g,c,hc0,hs0,hc1,hs1,hc2,hs2,hcx,hsx,hc4,hs4); __syncthreads();
  do_iter<1>(S,g,c,hc0,hs0,hc1,hs1,hc2,hs2,hcx,hsx,hc4,hs4); __syncthreads();
  do_iter<0>(S,g,c,hc0,hs0,hc1,hs1,hc2,hs2,hcx,hsx,hc4,hs4); __syncthreads();

  // Measurement with final CNOT block folded into parity masks
  float a12[12];
  #pragma unroll
  for (int w = 0; w < 12; ++w) a12[w] = 0.f;
  #pragma unroll
  for (int j = 0; j < 16; ++j){
    int l = t + 64*j;
    cplx v = S[l ^ ((l >> 5) & 31)];
    float p = v.x*v.x + v.y*v.y;
    int idx = (chunk << 10) | l;
    #pragma unroll
    for (int w = 0; w < 12; ++w)
      a12[w] += (__popc(idx & (27u << (11 - w))) & 1) ? -p : p;
  }
  #pragma unroll
  for (int off = 32; off > 0; off >>= 1)
    #pragma unroll
    for (int w = 0; w < 12; ++w)
      a12[w] += __shfl_down(a12[w], off, 64);
  if (t == 0){
    #pragma unroll
    for (int w = 0; w < 12; ++w)
      atomicAdd(&acc[pair*12 + w], a12[w]);
  }
}

__global__ __launch_bounds__(256) void mlp_kernel(
    const float* __restrict__ acc,
    const float* __restrict__ w1, const float* __restrict__ b1,
    const float* __restrict__ w2, const float* __restrict__ b2,
    const float* __restrict__ w3, const float* __restrict__ b3,
    float* __restrict__ out)
{
  __shared__ float feats[16*24];
  __shared__ float h1[16*128];
  __shared__ float h2[16*64];
  int tid = threadIdx.x;
  for (int e = tid; e < 384; e += 256){
    int w = e % 12, p = e / 12;          // p = k*16+b
    int bb = p & 15, kk = p >> 4;
    feats[bb*24 + kk*12 + w] = acc[p*12 + w];
  }
  __syncthreads();
  for (int e = tid; e < 2048; e += 256){
    int bb = e >> 7, j = e & 127;
    float s = b1[j];
    #pragma unroll 8
    for (int q = 0; q < 24; ++q) s = fmaf(feats[bb*24 + q], w1[j*24 + q], s);
    h1[e] = fmaxf(s, 0.f);
  }
  __syncthreads();
  for (int e = tid; e < 1024; e += 256){
    int bb = e >> 6, j = e & 63;
    float s = b2[j];
    #pragma unroll 8
    for (int q = 0; q < 128; ++q) s = fmaf(h1[bb*128 + q], w2[j*128 + q], s);
    h2[e] = fmaxf(s, 0.f);
  }
  __syncthreads();
  if (tid < 64){
    int bb = tid >> 2, j = tid & 3;
    float s = b3[j];
    #pragma unroll 8
    for (int q = 0; q < 64; ++q) s = fmaf(h2[bb*64 + q], w3[j*64 + q], s);
    out[tid] = s;
  }
}

extern "C" void kernel_launch(void* const* d_in, const int* in_sizes, int n_in,
                              void* d_out, int out_size, void* d_ws, size_t ws_size,
                              hipStream_t stream) {
  const float* x  = (const float*)d_in[0];
  const float* kp = (const float*)d_in[1];
  const float* w1 = (const float*)d_in[2];
  const float* b1 = (const float*)d_in[3];
  const float* w2 = (const float*)d_in[4];
  const float* b2 = (const float*)d_in[5];
  const float* w3 = (const float*)d_in[6];
  const float* b3 = (const float*)d_in[7];
  float* out = (float*)d_out;

  cplx*  psi_g = (cplx*)d_ws;                              // 32*1024 cplx = 256 KB
  float* cs    = (float*)((char*)d_ws + 32*1024*8);        // 16*32 floats
  float* acc   = (float*)((char*)d_ws + 32*1024*8 + 2048); // 384 floats

  stage1_kernel<<<32, 64, 0, stream>>>(x, kp, psi_g, cs, acc);
  stage3_kernel<<<2048, 64, 0, stream>>>(psi_g, cs, kp, acc);
  mlp_kernel<<<1, 256, 0, stream>>>(acc, w1, b1, w2, b2, w3, b3, out);
}

// Round 5
// 125.108 us; speedup vs baseline: 1.0766x; 1.0766x over previous
//
#include <hip/hip_runtime.h>
#include <math.h>

typedef float2 cplx;
__device__ __forceinline__ cplx mk(float r, float i){ return make_float2(r, i); }

// 1024-amp state held as 16 cplx regs per lane across a 64-lane wave.
// index n (10 bits): n9=L5 n8=L4 n7=L3 | n6=r3 n5=r2 n4=r1 n3=r0 | n2=L2 n1=L1 n0=L0
// i.e. n = ((lane>>3)<<7) | (r<<3) | (lane&7).
// Gate pass: rotation (RY or RX) pairing amplitudes across n-bit PB, with optional
// CNOT control on n-bit CB (control=1 => inputs swapped before rotation). CB=-1: none.
// reg bits: 3..6 (reg-bit PB-3). lane bits: {0,1,2,7,8,9} -> lane-idx bit (b<3? b : b-4).
template<int PB, int CB, bool ISRX>
__device__ __forceinline__ void gate_pass(cplx* A, float c, float s, int lane)
{
  if constexpr (PB >= 3 && PB <= 6) {
    constexpr int RM = 1 << (PB - 3);
    bool cl = false;
    if constexpr (CB >= 0 && !(CB >= 3 && CB <= 6)) {
      constexpr int LB = (CB < 3) ? CB : CB - 4;
      cl = (lane >> LB) & 1;
    }
    #pragma unroll
    for (int r = 0; r < 16; ++r) {
      if (r & RM) continue;
      cplx a0 = A[r], a1 = A[r | RM];
      bool sw;
      if constexpr (CB < 0) sw = false;
      else if constexpr (CB >= 3 && CB <= 6) sw = (r >> (CB - 3)) & 1;
      else sw = cl;
      float i0x = sw ? a1.x : a0.x, i0y = sw ? a1.y : a0.y;
      float i1x = sw ? a0.x : a1.x, i1y = sw ? a0.y : a1.y;
      if constexpr (ISRX) {
        // RX: (i0,i1) -> (c*i0 - i s*i1, -i s*i0 + c*i1)
        A[r]      = mk(fmaf(s, i1y, c*i0x), fmaf(-s, i1x, c*i0y));
        A[r | RM] = mk(fmaf(s, i0y, c*i1x), fmaf(-s, i0x, c*i1y));
      } else {
        // RY: (i0,i1) -> (c*i0 - s*i1, s*i0 + c*i1)
        A[r]      = mk(fmaf(-s, i1x, c*i0x), fmaf(-s, i1y, c*i0y));
        A[r | RM] = mk(fmaf( s, i0x, c*i1x), fmaf( s, i0y, c*i1y));
      }
    }
  } else {
    constexpr int LB = (PB < 3) ? PB : PB - 4;
    constexpr int M = 1 << LB;
    const int mybit = (lane >> LB) & 1;
    const float ssy = mybit ? s : -s;
    #pragma unroll
    for (int r = 0; r < 16; ++r) {
      float px = __shfl_xor(A[r].x, M, 64);
      float py = __shfl_xor(A[r].y, M, 64);
      bool sw = false;
      if constexpr (CB >= 3 && CB <= 6) sw = (r >> (CB - 3)) & 1;
      float ox = A[r].x, oy = A[r].y;
      float ux = sw ? px : ox, uy = sw ? py : oy;
      float vx = sw ? ox : px, vy = sw ? oy : py;
      if constexpr (ISRX) {
        // same formula for both sides of an RX pair (verified algebraically)
        A[r] = mk(fmaf(s, vy, c*ux), fmaf(-s, vx, c*uy));
      } else {
        A[r] = mk(fmaf(ssy, vx, c*ux), fmaf(ssy, vy, c*uy));
      }
    }
  }
}

// One fused conv iteration, window at bits LO..LO+4 (bit LO+4 = wire i):
// P1 RY0@i; P2 RY1@i+3 ctl i; P3 RY2@i+1; P4 RX0@i+4 ctl i+1; P5 RX1@i+1 ctl i+3.
template<int LO>
__device__ __forceinline__ void iter_reg(cplx* A, int lane,
    float c0,float s0,float c1,float s1,float c2,float s2,
    float cx,float sx,float c4,float s4)
{
  gate_pass<LO+4, -1,   false>(A, c0, s0, lane);
  gate_pass<LO+1, LO+4, false>(A, c1, s1, lane);
  gate_pass<LO+3, -1,   false>(A, c2, s2, lane);
  gate_pass<LO,   LO+3, true >(A, cx, sx, lane);
  gate_pass<LO+3, LO+1, true >(A, c4, s4, lane);
}

#define RUN6(A) \
  iter_reg<5>(A, lane, hc0,hs0,hc1,hs1,hc2,hs2,hcx,hsx,hc4,hs4); \
  iter_reg<4>(A, lane, hc0,hs0,hc1,hs1,hc2,hs2,hcx,hsx,hc4,hs4); \
  iter_reg<3>(A, lane, hc0,hs0,hc1,hs1,hc2,hs2,hcx,hsx,hc4,hs4); \
  iter_reg<2>(A, lane, hc0,hs0,hc1,hs1,hc2,hs2,hcx,hsx,hc4,hs4); \
  iter_reg<1>(A, lane, hc0,hs0,hc1,hs1,hc2,hs2,hcx,hsx,hc4,hs4); \
  iter_reg<0>(A, lane, hc0,hs0,hc1,hs1,hc2,hs2,hcx,hsx,hc4,hs4);

__global__ __launch_bounds__(256) void hybrid_kernel(
    const float* __restrict__ x, const float* __restrict__ kp,
    float* __restrict__ pacc,     // 2048 rows x 12 floats
    unsigned* __restrict__ cnt,   // memset 0 before launch
    const float* __restrict__ w1, const float* __restrict__ b1,
    const float* __restrict__ w2, const float* __restrict__ b2,
    const float* __restrict__ w3, const float* __restrict__ b3,
    float* __restrict__ out)
{
  __shared__ __align__(16) float lds[8320]; // 4 waves x (1024 cplx psi) + 4 x 32 angles
  __shared__ int isLast;

  const int tid  = threadIdx.x;
  const int wv   = tid >> 6;
  const int lane = tid & 63;
  const int gw   = blockIdx.x * 4 + wv;     // global wave 0..2047
  const int pair = gw & 31;                 // k*16 + b
  const int chunk = gw >> 5;                // wires 0..5 values
  const int b = pair & 15, k = pair >> 4;

  cplx*  P    = (cplx*)&lds[wv * 2048];
  float* angw = &lds[8192 + wv * 32];

  // ---- avgpool angles: lane = a*4 + q ----
  {
    int a = lane >> 2, q = lane & 3;
    int ii = a >> 2, jj = a & 3;
    const float* xb = x + b*784 + ii*7*28 + jj*7;
    float s = 0.f;
    for (int e = q; e < 49; e += 4)
      s += xb[(e/7)*28 + (e%7)];
    s += __shfl_xor(s, 1, 64);
    s += __shfl_xor(s, 2, 64);
    float ang = s * (1.0f/49.0f) * 0.5f;
    float cc = cosf(ang), ss = sinf(ang);
    if (q == 0){ angw[a*2] = cc; angw[a*2+1] = ss; }
  }

  // ---- conv params (wave-uniform) ----
  const float* p5 = kp + k*5;
  float hc0 = cosf(p5[0]*0.5f), hs0 = sinf(p5[0]*0.5f);
  float hc1 = cosf(p5[1]*0.5f), hs1 = sinf(p5[1]*0.5f);
  float hc2 = cosf(p5[2]*0.5f), hs2 = sinf(p5[2]*0.5f);
  float hcx = cosf(p5[3]*0.5f), hsx = sinf(p5[3]*0.5f);
  float hc4 = cosf(p5[4]*0.5f), hs4 = sinf(p5[4]*0.5f);

  __threadfence_block();  // angw writes visible to own wave's reads

  cplx A[16];

  // ---- stage 1: Psi over wires 0..9 (h bit 9-w), h=(lane,r) layout ----
  {
    // lane product: wires 0,1,2 (L5,L4,L3), wires 7,8,9 (L2,L1,L0)
    float lp = 1.f;
    lp *= ((lane>>5)&1) ? angw[1]  : angw[0];    // wire0
    lp *= ((lane>>4)&1) ? angw[3]  : angw[2];    // wire1
    lp *= ((lane>>3)&1) ? angw[5]  : angw[4];    // wire2
    lp *= ((lane>>2)&1) ? angw[15] : angw[14];   // wire7
    lp *= ((lane>>1)&1) ? angw[17] : angw[16];   // wire8
    lp *= ( lane     &1) ? angw[19] : angw[18];  // wire9
    float c3 = angw[6],  s3 = angw[7];   // wire3 (r bit3)
    float c4w= angw[8],  s4w= angw[9];   // wire4 (r bit2)
    float c5 = angw[10], s5 = angw[11];  // wire5 (r bit1)
    float c6 = angw[12], s6 = angw[13];  // wire6 (r bit0)
    #pragma unroll
    for (int r = 0; r < 16; ++r){
      float rp = ((r&8)? s3:c3) * ((r&4)? s4w:c4w) * ((r&2)? s5:c5) * ((r&1)? s6:c6);
      A[r] = mk(lp * rp, 0.f);
    }
    RUN6(A);
  }

  // ---- dump Psi to LDS (conflict-free), gather this chunk's 2 values ----
  #pragma unroll
  for (int r = 0; r < 16; ++r)
    P[(r << 6) | lane] = A[r];
  __threadfence_block();

  {
    int lh = lane >> 3, ll = lane & 7;
    cplx ps0, ps1;
    {
      int h = (chunk << 4) | (lh << 1);
      ps0 = P[((((h >> 3) & 15) << 6)) | (((h >> 7) << 3) | (h & 7))];
      h |= 1;
      ps1 = P[((((h >> 3) & 15) << 6)) | (((h >> 7) << 3) | (h & 7))];
    }
    // Pre: wires 10,11,12 on r bits 2,1,0; wires 13,14,15 on L2,L1,L0
    float c10 = angw[20], s10 = angw[21];
    float c11 = angw[22], s11 = angw[23];
    float c12 = angw[24], s12 = angw[25];
    float preL = 1.f;
    preL *= ((lane>>2)&1) ? angw[27] : angw[26]; // wire13
    preL *= ((lane>>1)&1) ? angw[29] : angw[28]; // wire14
    preL *= ( lane    &1) ? angw[31] : angw[30]; // wire15
    #pragma unroll
    for (int r = 0; r < 16; ++r){
      float f = preL * (((r&4)? s10:c10) * ((r&2)? s11:c11) * ((r&1)? s12:c12));
      cplx v = (r & 8) ? ps1 : ps0;
      A[r] = mk(v.x * f, v.y * f);
    }
  }

  // ---- stage 3: iterations 6..11 on local bits 9..0 (wire w -> bit 15-w) ----
  RUN6(A);

  // ---- measurement: E[Z_w] with final CNOT block folded into parity masks ----
  {
    int idx_hi = (chunk << 10) | ((lane >> 3) << 7) | (lane & 7);
    float p[16];
    #pragma unroll
    for (int r = 0; r < 16; ++r) p[r] = A[r].x*A[r].x + A[r].y*A[r].y;
    float a12[12];
    #pragma unroll
    for (int w = 0; w < 12; ++w){
      float s = 0.f;
      #pragma unroll
      for (int r = 0; r < 16; ++r){
        if (__popc((r << 3) & (27 << (11 - w))) & 1) s -= p[r]; else s += p[r];
      }
      a12[w] = (__popc(idx_hi & (27 << (11 - w))) & 1) ? -s : s;
    }
    #pragma unroll
    for (int off = 32; off > 0; off >>= 1)
      #pragma unroll
      for (int w = 0; w < 12; ++w)
        a12[w] += __shfl_xor(a12[w], off, 64);
    if (lane == 0){
      #pragma unroll
      for (int w = 0; w < 12; ++w)
        __hip_atomic_store(&pacc[gw*12 + w], a12[w], __ATOMIC_RELAXED, __HIP_MEMORY_SCOPE_AGENT);
    }
  }

  // ---- last-block election ----
  __syncthreads();
  if (tid == 0){
    __threadfence();
    unsigned old = __hip_atomic_fetch_add(cnt, 1u, __ATOMIC_ACQ_REL, __HIP_MEMORY_SCOPE_AGENT);
    isLast = (old == 511u);
  }
  __syncthreads();
  if (!isLast) return;
  __threadfence();

  // ---- winner: reduce partials (sum over chunk) + MLP, 256 threads ----
  float* feats = lds;          // 16*24
  float* h1    = lds + 384;    // 16*128
  float* h2    = lds + 2432;   // 16*64
  {
    int pr = tid >> 3, part = tid & 7;
    float sm[12];
    #pragma unroll
    for (int w = 0; w < 12; ++w) sm[w] = 0.f;
    for (int c = part; c < 64; c += 8){
      const float* row = pacc + ((c << 5) | pr) * 12;
      #pragma unroll
      for (int w = 0; w < 12; ++w)
        sm[w] += __hip_atomic_load(&row[w], __ATOMIC_RELAXED, __HIP_MEMORY_SCOPE_AGENT);
    }
    #pragma unroll
    for (int off = 1; off < 8; off <<= 1)
      #pragma unroll
      for (int w = 0; w < 12; ++w)
        sm[w] += __shfl_xor(sm[w], off, 64);
    __syncthreads();   // lds reuse: all sim data dead
    if (part == 0){
      int bb = pr & 15, kk = pr >> 4;
      #pragma unroll
      for (int w = 0; w < 12; ++w)
        feats[bb*24 + kk*12 + w] = sm[w];
    }
  }
  __syncthreads();
  for (int e = tid; e < 2048; e += 256){
    int bb = e >> 7, j = e & 127;
    const float4* wr = (const float4*)(w1 + j*24);
    const float4* fr = (const float4*)(feats + bb*24);
    float s = b1[j];
    #pragma unroll
    for (int q = 0; q < 6; ++q){
      float4 a = fr[q], w4 = wr[q];
      s += a.x*w4.x + a.y*w4.y + a.z*w4.z + a.w*w4.w;
    }
    h1[e] = fmaxf(s, 0.f);
  }
  __syncthreads();
  for (int e = tid; e < 1024; e += 256){
    int bb = e >> 6, j = e & 63;
    const float4* wr = (const float4*)(w2 + j*128);
    const float4* hr = (const float4*)(h1 + bb*128);
    float s = b2[j];
    #pragma unroll
    for (int q = 0; q < 32; ++q){
      float4 a = hr[q], w4 = wr[q];
      s += a.x*w4.x + a.y*w4.y + a.z*w4.z + a.w*w4.w;
    }
    h2[e] = fmaxf(s, 0.f);
  }
  __syncthreads();
  if (tid < 64){
    int bb = tid >> 2, j = tid & 3;
    const float4* wr = (const float4*)(w3 + j*64);
    const float4* hr = (const float4*)(h2 + bb*64);
    float s = b3[j];
    #pragma unroll
    for (int q = 0; q < 16; ++q){
      float4 a = hr[q], w4 = wr[q];
      s += a.x*w4.x + a.y*w4.y + a.z*w4.z + a.w*w4.w;
    }
    out[tid] = s;
  }
}

extern "C" void kernel_launch(void* const* d_in, const int* in_sizes, int n_in,
                              void* d_out, int out_size, void* d_ws, size_t ws_size,
                              hipStream_t stream) {
  const float* x  = (const float*)d_in[0];
  const float* kp = (const float*)d_in[1];
  const float* w1 = (const float*)d_in[2];
  const float* b1 = (const float*)d_in[3];
  const float* w2 = (const float*)d_in[4];
  const float* b2 = (const float*)d_in[5];
  const float* w3 = (const float*)d_in[6];
  const float* b3 = (const float*)d_in[7];
  float* out = (float*)d_out;

  float* pacc = (float*)d_ws;                            // 2048*12 floats = 96 KB
  unsigned* cnt = (unsigned*)((char*)d_ws + 2048*12*4);  // arrival counter

  hipMemsetAsync(cnt, 0, sizeof(unsigned), stream);
  hybrid_kernel<<<512, 256, 0, stream>>>(x, kp, pacc, cnt, w1, b1, w2, b2, w3, b3, out);
}

// Round 6
// 99.480 us; speedup vs baseline: 1.3539x; 1.2576x over previous
//
#include <hip/hip_runtime.h>
#include <math.h>

typedef float2 cplx;
__device__ __forceinline__ cplx mk(float r, float i){ return make_float2(r, i); }

// ---------------- state layout ----------------
// 1024-amp state per wave: 16 cplx regs x 64 lanes.
// state index n (10 bits): reg r = n[6:3] (r3=n6,r2=n5,r1=n4,r0=n3)
// lane bits: n7->L0, n8->L1, n2->L2, n1->L3, n0->L4, n9->L5
// so n = (L5<<9)|(L1<<8)|(L0<<7)|(r<<3)|(L2<<2)|(L3<<1)|L4
template<int B> struct LSH {
  static constexpr int v = (B==7)?0 : (B==8)?1 : (B==2)?2 : (B==1)?3 : (B==0)?4 : 5;
};

// lane exchange across state bit PB (PB in {0,1,2,7,8,9})
template<int PB>
__device__ __forceinline__ float lx(float v){
  if constexpr (PB == 7)       // lane xor 1: DPP quad_perm [1,0,3,2]
    return __int_as_float(__builtin_amdgcn_update_dpp(
        __float_as_int(v), __float_as_int(v), 0xB1, 0xF, 0xF, false));
  else if constexpr (PB == 8)  // lane xor 2: DPP quad_perm [2,3,0,1]
    return __int_as_float(__builtin_amdgcn_update_dpp(
        __float_as_int(v), __float_as_int(v), 0x4E, 0xF, 0xF, false));
  else if constexpr (PB == 2)  // lane xor 4
    return __int_as_float(__builtin_amdgcn_ds_swizzle(__float_as_int(v), 0x101F));
  else if constexpr (PB == 1)  // lane xor 8
    return __int_as_float(__builtin_amdgcn_ds_swizzle(__float_as_int(v), 0x201F));
  else if constexpr (PB == 0)  // lane xor 16
    return __int_as_float(__builtin_amdgcn_ds_swizzle(__float_as_int(v), 0x401F));
  else                         // PB == 9: lane xor 32
    return __shfl_xor(v, 32, 64);
}

// Rotation (RY or RX) pairing amplitudes across state bit PB, optional CNOT
// control on state bit CB (control=1 => inputs swapped). CB=-1: none.
// NOTE: with reg bits {3..6}, lane-exchange passes always have reg (or no)
// control; lane controls only occur on reg-exchange passes.
template<int PB, int CB, bool ISRX>
__device__ __forceinline__ void gate_pass(cplx* A, float c, float s, int lane)
{
  if constexpr (PB >= 3 && PB <= 6) {
    constexpr int RM = 1 << (PB - 3);
    bool cl = false;
    if constexpr (CB >= 0 && !(CB >= 3 && CB <= 6))
      cl = (lane >> LSH<CB>::v) & 1;
    #pragma unroll
    for (int r = 0; r < 16; ++r) {
      if (r & RM) continue;
      cplx a0 = A[r], a1 = A[r | RM];
      bool sw;
      if constexpr (CB < 0) sw = false;
      else if constexpr (CB >= 3 && CB <= 6) sw = (r >> (CB - 3)) & 1;
      else sw = cl;
      float i0x = sw ? a1.x : a0.x, i0y = sw ? a1.y : a0.y;
      float i1x = sw ? a0.x : a1.x, i1y = sw ? a0.y : a1.y;
      if constexpr (ISRX) {
        A[r]      = mk(fmaf(s, i1y, c*i0x), fmaf(-s, i1x, c*i0y));
        A[r | RM] = mk(fmaf(s, i0y, c*i1x), fmaf(-s, i0x, c*i1y));
      } else {
        A[r]      = mk(fmaf(-s, i1x, c*i0x), fmaf(-s, i1y, c*i0y));
        A[r | RM] = mk(fmaf( s, i0x, c*i1x), fmaf( s, i0y, c*i1y));
      }
    }
  } else {
    const int mybit = (lane >> LSH<PB>::v) & 1;
    const float ssy = mybit ? s : -s;
    #pragma unroll
    for (int r = 0; r < 16; ++r) {
      float px = lx<PB>(A[r].x);
      float py = lx<PB>(A[r].y);
      bool sw = false;
      if constexpr (CB >= 3 && CB <= 6) sw = (r >> (CB - 3)) & 1;
      float ox = A[r].x, oy = A[r].y;
      float ux = sw ? px : ox, uy = sw ? py : oy;
      float vx = sw ? ox : px, vy = sw ? oy : py;
      if constexpr (ISRX) A[r] = mk(fmaf(s, vy, c*ux), fmaf(-s, vx, c*uy));
      else                A[r] = mk(fmaf(ssy, vx, c*ux), fmaf(ssy, vy, c*uy));
    }
  }
}

// One fused conv iteration, window bits LO..LO+4 (bit LO+4 = wire i):
// RY0@i; RY1@i+3 ctl i; RY2@i+1; RX0@i+4 ctl i+1; RX1@i+1 ctl i+3.
template<int LO>
__device__ __forceinline__ void iter_reg(cplx* A, int lane,
    float c0,float s0,float c1,float s1,float c2,float s2,
    float cx,float sx,float c4,float s4)
{
  gate_pass<LO+4, -1,   false>(A, c0, s0, lane);
  gate_pass<LO+1, LO+4, false>(A, c1, s1, lane);
  gate_pass<LO+3, -1,   false>(A, c2, s2, lane);
  gate_pass<LO,   LO+3, true >(A, cx, sx, lane);
  gate_pass<LO+3, LO+1, true >(A, c4, s4, lane);
}

#define RUN6(A) \
  iter_reg<5>(A, lane, hc0,hs0,hc1,hs1,hc2,hs2,hcx,hsx,hc4,hs4); \
  iter_reg<4>(A, lane, hc0,hs0,hc1,hs1,hc2,hs2,hcx,hsx,hc4,hs4); \
  iter_reg<3>(A, lane, hc0,hs0,hc1,hs1,hc2,hs2,hcx,hsx,hc4,hs4); \
  iter_reg<2>(A, lane, hc0,hs0,hc1,hs1,hc2,hs2,hcx,hsx,hc4,hs4); \
  iter_reg<1>(A, lane, hc0,hs0,hc1,hs1,hc2,hs2,hcx,hsx,hc4,hs4); \
  iter_reg<0>(A, lane, hc0,hs0,hc1,hs1,hc2,hs2,hcx,hsx,hc4,hs4);

__device__ __forceinline__ float wave_sum(float v){
  v += lx<7>(v);            // xor1 (DPP)
  v += lx<8>(v);            // xor2 (DPP)
  v += lx<2>(v);            // xor4
  v += lx<1>(v);            // xor8
  v += lx<0>(v);            // xor16
  v += __shfl_xor(v, 32, 64);
  return v;
}

__global__ __launch_bounds__(256) void sim_kernel(
    const float* __restrict__ x, const float* __restrict__ kp,
    float* __restrict__ pacc)   // 2048 rows x 12 floats, row gw = pair*64+chunk
{
  __shared__ __align__(16) float lds[8320]; // 4 waves x 1024 cplx + 4 x 32 angles

  const int tid = threadIdx.x, wv = tid >> 6, lane = tid & 63;
  const int gw = blockIdx.x * 4 + wv;
  const int pair = gw >> 6;      // k*16 + b
  const int chunk = gw & 63;     // wires 0..5: wire w = (chunk>>(5-w))&1
  const int b = pair & 15, k = pair >> 4;

  cplx*  P    = (cplx*)&lds[wv * 2048];
  float* angw = &lds[8192 + wv * 32];

  // ---- avgpool -> (cos,sin) of half-angles, 16 wires ----
  {
    int a = lane >> 2, q = lane & 3;
    int ii = a >> 2, jj = a & 3;
    const float* xb = x + b*784 + ii*7*28 + jj*7;
    float s = 0.f;
    for (int e = q; e < 49; e += 4) s += xb[(e/7)*28 + (e%7)];
    s += __shfl_xor(s, 1, 64);
    s += __shfl_xor(s, 2, 64);
    float ang = s * (1.0f/49.0f) * 0.5f;
    if (q == 0){ angw[a*2] = cosf(ang); angw[a*2+1] = sinf(ang); }
  }

  const float* p5 = kp + k*5;
  float hc0 = cosf(p5[0]*0.5f), hs0 = sinf(p5[0]*0.5f);
  float hc1 = cosf(p5[1]*0.5f), hs1 = sinf(p5[1]*0.5f);
  float hc2 = cosf(p5[2]*0.5f), hs2 = sinf(p5[2]*0.5f);
  float hcx = cosf(p5[3]*0.5f), hsx = sinf(p5[3]*0.5f);
  float hc4 = cosf(p5[4]*0.5f), hs4 = sinf(p5[4]*0.5f);

  __threadfence_block();

  cplx A[16];

  // ---- stage 1: Psi over wires 0..9 (wire w -> n bit 9-w) ----
  {
    float lp = 1.f;
    lp *= ((lane>>5)&1) ? angw[1]  : angw[0];    // wire0 (n9=L5)
    lp *= ((lane>>1)&1) ? angw[3]  : angw[2];    // wire1 (n8=L1)
    lp *= ( lane    &1) ? angw[5]  : angw[4];    // wire2 (n7=L0)
    lp *= ((lane>>2)&1) ? angw[15] : angw[14];   // wire7 (n2=L2)
    lp *= ((lane>>3)&1) ? angw[17] : angw[16];   // wire8 (n1=L3)
    lp *= ((lane>>4)&1) ? angw[19] : angw[18];   // wire9 (n0=L4)
    float c3 = angw[6],  s3 = angw[7];   // wire3 (r3)
    float c4w= angw[8],  s4w= angw[9];   // wire4 (r2)
    float c5 = angw[10], s5 = angw[11];  // wire5 (r1)
    float c6 = angw[12], s6 = angw[13];  // wire6 (r0)
    #pragma unroll
    for (int r = 0; r < 16; ++r){
      float rp = ((r&8)? s3:c3) * ((r&4)? s4w:c4w) * ((r&2)? s5:c5) * ((r&1)? s6:c6);
      A[r] = mk(lp * rp, 0.f);
    }
  }
  RUN6(A);   // iterations 0..5 (wire w -> bit 9-w, iter i: LO = 5-i)

  // ---- dump Psi to per-wave LDS, gather this chunk's 16-value window ----
  #pragma unroll
  for (int r = 0; r < 16; ++r) P[(r << 6) | lane] = A[r];
  __threadfence_block();
  {
    // needed Psi index h = (chunk<<4) | j ; j3=wire6, j2=wire7, j1=wire8, j0=wire9
    // stage-3 state: wire6->n9(L5), wire7->n8(L1), wire8->n7(L0), wire9->n6(r3)
    int jc = (((lane>>5)&1) << 2) | (((lane>>1)&1) << 1) | (lane & 1);
    int h0 = (chunk << 4) | (jc << 1);
    int r0_ = (h0 >> 3) & 15;
    int l0_ = ((h0>>7)&1) | (((h0>>8)&1)<<1) | (((h0>>2)&1)<<2)
            | (((h0>>1)&1)<<3) | ((h0&1)<<4) | (((h0>>9)&1)<<5);
    cplx ps0 = P[(r0_ << 6) | l0_];
    cplx ps1 = P[(r0_ << 6) | l0_ | 16];   // h0|1 flips n bit0 -> lane bit 4

    // Pre over wires 10..15: wire10->r2, wire11->r1, wire12->r0,
    //                        wire13->L2, wire14->L3, wire15->L4
    float c10 = angw[20], s10 = angw[21];
    float c11 = angw[22], s11 = angw[23];
    float c12 = angw[24], s12 = angw[25];
    float preL = 1.f;
    preL *= ((lane>>2)&1) ? angw[27] : angw[26]; // wire13
    preL *= ((lane>>3)&1) ? angw[29] : angw[28]; // wire14
    preL *= ((lane>>4)&1) ? angw[31] : angw[30]; // wire15
    #pragma unroll
    for (int r = 0; r < 16; ++r){
      float f = preL * (((r&4)? s10:c10) * ((r&2)? s11:c11) * ((r&1)? s12:c12));
      cplx v = (r & 8) ? ps1 : ps0;
      A[r] = mk(v.x * f, v.y * f);
    }
  }

  RUN6(A);   // iterations 6..11 (wire w -> local bit 15-w, iter i: LO = 11-i)

  // ---- measurement: E[Z_w], final CNOT block folded into parity masks ----
  {
    int idx_hi = (chunk << 10)
      | (((lane>>5)&1) << 9) | (((lane>>1)&1) << 8) | ((lane & 1) << 7)
      | (((lane>>2)&1) << 2) | (((lane>>3)&1) << 1) | ((lane>>4)&1);
    float p[16];
    #pragma unroll
    for (int r = 0; r < 16; ++r) p[r] = A[r].x*A[r].x + A[r].y*A[r].y;
    float out12[12];
    #pragma unroll
    for (int w = 0; w < 12; ++w){
      float s = 0.f;
      #pragma unroll
      for (int r = 0; r < 16; ++r)
        s += (__popc((r << 3) & (27 << (11 - w))) & 1) ? -p[r] : p[r];
      s = (__popc(idx_hi & (27 << (11 - w))) & 1) ? -s : s;
      out12[w] = wave_sum(s);
    }
    if (lane == 0){
      float4* dst = (float4*)(pacc + gw*12);
      dst[0] = make_float4(out12[0], out12[1], out12[2],  out12[3]);
      dst[1] = make_float4(out12[4], out12[5], out12[6],  out12[7]);
      dst[2] = make_float4(out12[8], out12[9], out12[10], out12[11]);
    }
  }
}

__global__ __launch_bounds__(256) void mlp_kernel(
    const float* __restrict__ pacc,
    const float* __restrict__ w1, const float* __restrict__ b1,
    const float* __restrict__ w2, const float* __restrict__ b2,
    const float* __restrict__ w3, const float* __restrict__ b3,
    float* __restrict__ out)
{
  __shared__ float feats[16*24];
  __shared__ float h1[16*128];
  __shared__ float h2[16*64];
  int tid = threadIdx.x;

  // reduce pacc over 64 chunks per pair
  {
    int pr = tid >> 3, part = tid & 7;    // pr = pair (k*16+b)
    float sm[12];
    #pragma unroll
    for (int w = 0; w < 12; ++w) sm[w] = 0.f;
    for (int c = part; c < 64; c += 8){
      const float4* row = (const float4*)(pacc + (pr*64 + c)*12);
      float4 r0 = row[0], r1 = row[1], r2 = row[2];
      sm[0]+=r0.x; sm[1]+=r0.y; sm[2] +=r0.z; sm[3] +=r0.w;
      sm[4]+=r1.x; sm[5]+=r1.y; sm[6] +=r1.z; sm[7] +=r1.w;
      sm[8]+=r2.x; sm[9]+=r2.y; sm[10]+=r2.z; sm[11]+=r2.w;
    }
    #pragma unroll
    for (int m = 1; m < 8; m <<= 1)
      #pragma unroll
      for (int w = 0; w < 12; ++w)
        sm[w] += __shfl_xor(sm[w], m, 64);
    if (part == 0){
      int bb = pr & 15, kk = pr >> 4;
      #pragma unroll
      for (int w = 0; w < 12; ++w)
        feats[bb*24 + kk*12 + w] = sm[w];
    }
  }
  __syncthreads();

  for (int e = tid; e < 2048; e += 256){
    int bb = e >> 7, j = e & 127;
    const float4* wr = (const float4*)(w1 + j*24);
    const float4* fr = (const float4*)(feats + bb*24);
    float s = b1[j];
    #pragma unroll
    for (int q = 0; q < 6; ++q){
      float4 a = fr[q], w4 = wr[q];
      s += a.x*w4.x + a.y*w4.y + a.z*w4.z + a.w*w4.w;
    }
    h1[e] = fmaxf(s, 0.f);
  }
  __syncthreads();
  for (int e = tid; e < 1024; e += 256){
    int bb = e >> 6, j = e & 63;
    const float4* wr = (const float4*)(w2 + j*128);
    const float4* hr = (const float4*)(h1 + bb*128);
    float s = b2[j];
    #pragma unroll
    for (int q = 0; q < 32; ++q){
      float4 a = hr[q], w4 = wr[q];
      s += a.x*w4.x + a.y*w4.y + a.z*w4.z + a.w*w4.w;
    }
    h2[e] = fmaxf(s, 0.f);
  }
  __syncthreads();
  if (tid < 64){
    int bb = tid >> 2, j = tid & 3;
    const float4* wr = (const float4*)(w3 + j*64);
    const float4* hr = (const float4*)(h2 + bb*64);
    float s = b3[j];
    #pragma unroll
    for (int q = 0; q < 16; ++q){
      float4 a = hr[q], w4 = wr[q];
      s += a.x*w4.x + a.y*w4.y + a.z*w4.z + a.w*w4.w;
    }
    out[tid] = s;
  }
}

extern "C" void kernel_launch(void* const* d_in, const int* in_sizes, int n_in,
                              void* d_out, int out_size, void* d_ws, size_t ws_size,
                              hipStream_t stream) {
  const float* x  = (const float*)d_in[0];
  const float* kp = (const float*)d_in[1];
  const float* w1 = (const float*)d_in[2];
  const float* b1 = (const float*)d_in[3];
  const float* w2 = (const float*)d_in[4];
  const float* b2 = (const float*)d_in[5];
  const float* w3 = (const float*)d_in[6];
  const float* b3 = (const float*)d_in[7];
  float* out  = (float*)d_out;
  float* pacc = (float*)d_ws;   // 2048*12 floats = 96 KB

  sim_kernel<<<512, 256, 0, stream>>>(x, kp, pacc);
  mlp_kernel<<<1, 256, 0, stream>>>(pacc, w1, b1, w2, b2, w3, b3, out);
}